// Round 2
// baseline (2105.868 us; speedup 1.0000x reference)
//
#include <hip/hip_runtime.h>
#include <hip/hip_fp16.h>
#include <stdint.h>

#define K_DIM 4096
#define N_DIM 11008
#define WPR   (K_DIM / 8)     // 512 packed int32 words per output row
#define NGRP  (K_DIM / 128)   // 32 quant groups per row
#define BM 128
#define BN 128
#define BK 64
#define NKT (K_DIM / BK)      // 64 K-tiles
#define LDSP 72               // padded LDS row (halves): 144 B = 9*16 B

typedef _Float16 half8 __attribute__((ext_vector_type(8)));
typedef float floatx4 __attribute__((ext_vector_type(4)));

union H8 { __half2 h2[4]; half8 v; };

__global__ __launch_bounds__(256, 2)
void qlin_mfma(const float* __restrict__ x,
               const uint32_t* __restrict__ qw,
               const float* __restrict__ scales,   // harness normalizes f16 -> f32
               const float* __restrict__ biases,   // harness normalizes f16 -> f32
               const float* __restrict__ linb,     // harness normalizes f16 -> f32
               float* __restrict__ out)
{
    __shared__ _Float16 As[BM][LDSP];
    __shared__ _Float16 Bs[BN][LDSP];

    const int NBN = N_DIM / BN;             // 86
    const int bn = blockIdx.x % NBN;        // bn fastest: consecutive blocks share A panel
    const int bm = blockIdx.x / NBN;

    const int tid  = threadIdx.x;
    const int lane = tid & 63;
    const int wv   = tid >> 6;
    const int wm   = (wv >> 1) * 64;        // wave's M offset in tile
    const int wn   = (wv & 1) * 64;         // wave's N offset in tile

    // Staging assignment: thread t handles row t>>1 (for both A and B tiles),
    // half-row selected by t&1.
    const int srow  = tid >> 1;             // 0..127
    const int ahalf = (tid & 1) * 32;       // float offset within k-tile
    const int bw4   = (tid & 1) * 4;        // packed-word offset within k-tile

    const float*    aB = x  + (size_t)(bm * BM + srow) * K_DIM + ahalf;
    const uint32_t* qB = qw + (size_t)(bn * BN + srow) * WPR + bw4;
    const float*    sB = scales + (size_t)(bn * BN + srow) * NGRP;
    const float*    bB = biases + (size_t)(bn * BN + srow) * NGRP;

    floatx4 acc[4][4] = {};

    // prefetch registers
    float4  ar[8];
    uint4   qr;
    __half2 s2, b2;

    auto LOADT = [&](int kt) {
        const float4* ap = (const float4*)(aB + (size_t)kt * BK);
        #pragma unroll
        for (int i = 0; i < 8; ++i) ar[i] = ap[i];
        qr = *(const uint4*)(qB + kt * 8);
        const int g = kt >> 1;              // 64-K tile -> group kt/2 (never crosses)
        // f32 values round-trip exactly to f16 (they originated as f16)
        s2 = __half2half2(__float2half(sB[g]));
        b2 = __half2half2(__float2half(bB[g]));
    };

    auto STORET = [&]() {
        // A: fp32 -> fp16, k-interleaved within each 8-chunk: (x0,x4,x1,x5,x2,x6,x3,x7)
        #pragma unroll
        for (int c = 0; c < 4; ++c) {
            H8 h;
            h.h2[0] = __floats2half2_rn(ar[2*c].x, ar[2*c+1].x);
            h.h2[1] = __floats2half2_rn(ar[2*c].y, ar[2*c+1].y);
            h.h2[2] = __floats2half2_rn(ar[2*c].z, ar[2*c+1].z);
            h.h2[3] = __floats2half2_rn(ar[2*c].w, ar[2*c+1].w);
            *(half8*)&As[srow][ahalf + c * 8] = h.v;
        }
        // B: unpack 4 words (32 codes) with the same (c_p, c_{p+4}) interleave
        const __half2 c1024 = __float2half2_rn(1024.0f);
        const uint32_t uws[4] = {qr.x, qr.y, qr.z, qr.w};
        #pragma unroll
        for (int wi = 0; wi < 4; ++wi) {
            const uint32_t u = uws[wi];
            H8 h;
            #pragma unroll
            for (int p = 0; p < 4; ++p) {
                const uint32_t v = ((u >> (4 * p)) & 0x000F000Fu) | 0x64006400u;
                const __half2 q2 = __hsub2(__builtin_bit_cast(__half2, v), c1024);
                h.h2[p] = __hfma2(s2, q2, b2);   // w = s*q + b
            }
            *(half8*)&Bs[srow][bw4 * 8 + wi * 8] = h.v;
        }
    };

    auto COMPUTE = [&]() {
        #pragma unroll
        for (int ks = 0; ks < 2; ++ks) {
            half8 af[4], bf[4];
            const int ko = ks * 32 + (lane >> 4) * 8;
            const int fr = lane & 15;
            #pragma unroll
            for (int i = 0; i < 4; ++i)
                af[i] = *(const half8*)&As[wm + i * 16 + fr][ko];
            #pragma unroll
            for (int i = 0; i < 4; ++i)
                bf[i] = *(const half8*)&Bs[wn + i * 16 + fr][ko];
            #pragma unroll
            for (int mf = 0; mf < 4; ++mf)
                #pragma unroll
                for (int nf = 0; nf < 4; ++nf)
                    acc[mf][nf] = __builtin_amdgcn_mfma_f32_16x16x32_f16(
                        af[mf], bf[nf], acc[mf][nf], 0, 0, 0);
        }
    };

    LOADT(0);
    STORET();
    __syncthreads();
    for (int kt = 1; kt < NKT; ++kt) {
        LOADT(kt);          // next tile's global loads in flight during compute
        COMPUTE();          // consume tile kt-1 from LDS
        __syncthreads();    // all LDS reads done before overwrite
        STORET();
        __syncthreads();    // writes visible
    }
    COMPUTE();

    // Epilogue: C/D layout col = lane&15, row = (lane>>4)*4 + j  [m89/m91 verified]
    const int rb = bm * BM + wm + ((lane >> 4) << 2);
    const int cb = bn * BN + wn + (lane & 15);
    #pragma unroll
    for (int nf = 0; nf < 4; ++nf) {
        const int col = cb + nf * 16;
        const float lb = linb[col];
        #pragma unroll
        for (int mf = 0; mf < 4; ++mf) {
            const int row = rb + mf * 16;
            #pragma unroll
            for (int j = 0; j < 4; ++j)
                out[(size_t)(row + j) * N_DIM + col] = acc[mf][nf][j] + lb;
        }
    }
}

extern "C" void kernel_launch(void* const* d_in, const int* in_sizes, int n_in,
                              void* d_out, int out_size, void* d_ws, size_t ws_size,
                              hipStream_t stream) {
    const float*    x      = (const float*)d_in[0];
    const uint32_t* qw     = (const uint32_t*)d_in[1];
    const float*    scales = (const float*)d_in[2];
    const float*    biases = (const float*)d_in[3];
    const float*    linb   = (const float*)d_in[4];
    float*          out    = (float*)d_out;

    const int M = in_sizes[0] / K_DIM;      // 4*2048 = 8192, multiple of BM
    dim3 grid((M / BM) * (N_DIM / BN));     // 64 * 86 = 5504
    qlin_mfma<<<grid, 256, 0, stream>>>(x, qw, scales, biases, linb, out);
}

// Round 3
// 1088.043 us; speedup vs baseline: 1.9355x; 1.9355x over previous
//
#include <hip/hip_runtime.h>
#include <hip/hip_fp16.h>
#include <stdint.h>

#define K_DIM 4096
#define N_DIM 11008
#define WPR   (K_DIM / 8)     // 512 packed int32 words per output row
#define NGRP  (K_DIM / 128)   // 32 quant groups per row
#define BM 128
#define BN 128
#define BK 64
#define NKT (K_DIM / BK)      // 64 K-tiles
#define LDSP 72               // fallback kernel pad

typedef _Float16 half8 __attribute__((ext_vector_type(8)));
typedef float floatx4 __attribute__((ext_vector_type(4)));
union H8 { __half2 h2[4]; half8 v; };

#define GLOAD16(g, l) __builtin_amdgcn_global_load_lds( \
    (const __attribute__((address_space(1))) uint32_t*)(g), \
    (__attribute__((address_space(3))) uint32_t*)(l), 16, 0, 0)

// ---------------- pre-pass: x f32 -> f16 into ws, k-interleaved per 8-chunk
// half order within each 8-chunk: (x0,x4,x1,x5,x2,x6,x3,x7) to match nibble unpack
__global__ __launch_bounds__(256)
void cvt_x(const float* __restrict__ x, _Float16* __restrict__ xh) {
    size_t i = (size_t)blockIdx.x * blockDim.x + threadIdx.x;  // one 8-chunk per thread
    const float4* p = (const float4*)(x + i * 8);
    float4 a = p[0], b = p[1];
    H8 h;
    h.h2[0] = __floats2half2_rn(a.x, b.x);
    h.h2[1] = __floats2half2_rn(a.y, b.y);
    h.h2[2] = __floats2half2_rn(a.z, b.z);
    h.h2[3] = __floats2half2_rn(a.w, b.w);
    *(half8*)(xh + i * 8) = h.v;
}

// ---------------- main: A=x(f16, ws) via global_load_lds, B=dequant(q4) reg-staged
__global__ __launch_bounds__(256, 2)
void qlin_f16(const _Float16* __restrict__ xh,
              const uint32_t* __restrict__ qw,
              const float* __restrict__ scales,
              const float* __restrict__ biases,
              const float* __restrict__ linb,
              float* __restrict__ out)
{
    __shared__ _Float16 As[2][BM * BK];   // linear dest; swizzled image via source perm
    __shared__ _Float16 Bs[2][BN * BK];   // swizzled write + swizzled read

    const int NBN = N_DIM / BN;           // 86
    const int bn = blockIdx.x % NBN;      // bn fastest: share A panel in L2
    const int bm = blockIdx.x / NBN;
    const int tid  = threadIdx.x;
    const int lane = tid & 63;
    const int wv   = tid >> 6;
    const int wm   = (wv >> 1) * 64;
    const int wn   = (wv & 1) * 64;

    // ---- A staging: wave wv, issue j, lane l -> LDS unit u = wv*256+j*64+l (16B units)
    // row = u>>3 = wv*32+j*8+(l>>3), lds chunk = l&7. Source chunk = (l&7)^(row&7).
    const int arow = wv * 32 + (lane >> 3);
    const int acs  = ((lane & 7) ^ ((lane >> 3) & 7)) * 8;  // halves
    const _Float16* aSrc = xh + (size_t)(bm * BM + arow) * K_DIM + acs;

    // ---- B staging: thread -> (row = tid>>1, 4 packed words at half bsel)
    const int srow = tid >> 1;
    const int bsel = tid & 1;
    const uint32_t* qB = qw + (size_t)(bn * BN + srow) * WPR + bsel * 4;
    const float*    sB = scales + (size_t)(bn * BN + srow) * NGRP;
    const float*    bB = biases + (size_t)(bn * BN + srow) * NGRP;
    const int bwbase = srow * BK;
    const int bswz   = srow & 7;

    floatx4 acc[4][4] = {};
    uint4 q0, q1; float s0, b0, s1, b1;

    auto LOADB = [&](uint4& qr, float& s, float& b, int kt) {
        qr = *(const uint4*)(qB + kt * 8);
        s = sB[kt >> 1];                  // BK=64 never crosses a 128-group
        b = bB[kt >> 1];
    };

    auto GLOADA = [&](int buf, int kt) {
        const _Float16* sp = aSrc + (size_t)kt * BK;
        #pragma unroll
        for (int j = 0; j < 4; ++j)
            GLOAD16(sp + (size_t)j * 8 * K_DIM, &As[buf][wv * 2048 + j * 512]);
    };

    auto DEQ = [&](const uint4& qr, float sf, float bf, int buf) {
        const __half2 s2 = __half2half2(__float2half(sf));
        const __half2 b2 = __half2half2(__float2half(bf));
        const __half2 c1024 = __float2half2_rn(1024.0f);
        const uint32_t uws[4] = {qr.x, qr.y, qr.z, qr.w};
        #pragma unroll
        for (int wi = 0; wi < 4; ++wi) {
            const uint32_t u = uws[wi];
            H8 h;
            #pragma unroll
            for (int p = 0; p < 4; ++p) {
                const uint32_t v = ((u >> (4 * p)) & 0x000F000Fu) | 0x64006400u;
                const __half2 q2 = __hsub2(__builtin_bit_cast(__half2, v), c1024);
                h.h2[p] = __hfma2(s2, q2, b2);
            }
            const int c = bsel * 4 + wi;
            *(half8*)&Bs[buf][bwbase + ((c ^ bswz) * 8)] = h.v;
        }
    };

    const int fr = lane & 15;
    const int kq = lane >> 4;

    auto COMPUTE = [&](int buf) {
        const _Float16* Ab = &As[buf][0];
        const _Float16* Bb = &Bs[buf][0];
        #pragma unroll
        for (int ks = 0; ks < 2; ++ks) {
            half8 af[4], bf[4];
            const int cs = ks * 4 + kq;
            #pragma unroll
            for (int i = 0; i < 4; ++i) {
                const int r = wm + i * 16 + fr;
                af[i] = *(const half8*)(Ab + r * BK + ((cs ^ (r & 7)) * 8));
            }
            #pragma unroll
            for (int i = 0; i < 4; ++i) {
                const int r = wn + i * 16 + fr;
                bf[i] = *(const half8*)(Bb + r * BK + ((cs ^ (r & 7)) * 8));
            }
            #pragma unroll
            for (int mf = 0; mf < 4; ++mf)
                #pragma unroll
                for (int nf = 0; nf < 4; ++nf)
                    acc[mf][nf] = __builtin_amdgcn_mfma_f32_16x16x32_f16(
                        af[mf], bf[nf], acc[mf][nf], 0, 0, 0);
        }
    };

    // prologue: stage tile 0 into buf0; raw tile 1 into q0
    LOADB(q0, s0, b0, 0);
    GLOADA(0, 0);
    DEQ(q0, s0, b0, 0);
    LOADB(q0, s0, b0, 1);
    __syncthreads();

    for (int kt = 0; kt < NKT; kt += 2) {
        // even half: compute tile kt (buf0); q0 holds raw kt+1
        GLOADA(1, kt + 1);
        if (kt + 2 < NKT) LOADB(q1, s1, b1, kt + 2);
        DEQ(q0, s0, b0, 1);
        COMPUTE(0);
        __syncthreads();
        // odd half: compute tile kt+1 (buf1); q1 holds raw kt+2
        if (kt + 2 < NKT) {
            GLOADA(0, kt + 2);
            if (kt + 3 < NKT) LOADB(q0, s0, b0, kt + 3);
            DEQ(q1, s1, b1, 0);
        }
        COMPUTE(1);
        if (kt + 2 < NKT) __syncthreads();
    }

    // epilogue: C/D layout col = lane&15, row = (lane>>4)*4 + j
    const int rb = bm * BM + wm + ((lane >> 4) << 2);
    const int cb = bn * BN + wn + (lane & 15);
    #pragma unroll
    for (int nf = 0; nf < 4; ++nf) {
        const int col = cb + nf * 16;
        const float lb = linb[col];
        #pragma unroll
        for (int mf = 0; mf < 4; ++mf) {
            const int row = rb + mf * 16;
            #pragma unroll
            for (int j = 0; j < 4; ++j)
                out[(size_t)(row + j) * N_DIM + col] = acc[mf][nf][j] + lb;
        }
    }
}

// ---------------- fallback (round-2 verified kernel) for small ws ----------------
__global__ __launch_bounds__(256, 2)
void qlin_mfma(const float* __restrict__ x,
               const uint32_t* __restrict__ qw,
               const float* __restrict__ scales,
               const float* __restrict__ biases,
               const float* __restrict__ linb,
               float* __restrict__ out)
{
    __shared__ _Float16 As2[BM][LDSP];
    __shared__ _Float16 Bs2[BN][LDSP];
    const int NBN = N_DIM / BN;
    const int bn = blockIdx.x % NBN;
    const int bm = blockIdx.x / NBN;
    const int tid  = threadIdx.x;
    const int lane = tid & 63;
    const int wv   = tid >> 6;
    const int wm   = (wv >> 1) * 64;
    const int wn   = (wv & 1) * 64;
    const int srow  = tid >> 1;
    const int ahalf = (tid & 1) * 32;
    const int bw4   = (tid & 1) * 4;
    const float*    aB = x  + (size_t)(bm * BM + srow) * K_DIM + ahalf;
    const uint32_t* qB = qw + (size_t)(bn * BN + srow) * WPR + bw4;
    const float*    sB = scales + (size_t)(bn * BN + srow) * NGRP;
    const float*    bB = biases + (size_t)(bn * BN + srow) * NGRP;
    floatx4 acc[4][4] = {};
    float4  ar[8]; uint4 qr; __half2 s2, b2;
    auto LOADT = [&](int kt) {
        const float4* ap = (const float4*)(aB + (size_t)kt * BK);
        #pragma unroll
        for (int i = 0; i < 8; ++i) ar[i] = ap[i];
        qr = *(const uint4*)(qB + kt * 8);
        const int g = kt >> 1;
        s2 = __half2half2(__float2half(sB[g]));
        b2 = __half2half2(__float2half(bB[g]));
    };
    auto STORET = [&]() {
        #pragma unroll
        for (int c = 0; c < 4; ++c) {
            H8 h;
            h.h2[0] = __floats2half2_rn(ar[2*c].x, ar[2*c+1].x);
            h.h2[1] = __floats2half2_rn(ar[2*c].y, ar[2*c+1].y);
            h.h2[2] = __floats2half2_rn(ar[2*c].z, ar[2*c+1].z);
            h.h2[3] = __floats2half2_rn(ar[2*c].w, ar[2*c+1].w);
            *(half8*)&As2[srow][ahalf + c * 8] = h.v;
        }
        const __half2 c1024 = __float2half2_rn(1024.0f);
        const uint32_t uws[4] = {qr.x, qr.y, qr.z, qr.w};
        #pragma unroll
        for (int wi = 0; wi < 4; ++wi) {
            const uint32_t u = uws[wi];
            H8 h;
            #pragma unroll
            for (int p = 0; p < 4; ++p) {
                const uint32_t v = ((u >> (4 * p)) & 0x000F000Fu) | 0x64006400u;
                const __half2 q2 = __hsub2(__builtin_bit_cast(__half2, v), c1024);
                h.h2[p] = __hfma2(s2, q2, b2);
            }
            *(half8*)&Bs2[srow][bw4 * 8 + wi * 8] = h.v;
        }
    };
    auto COMPUTE = [&]() {
        #pragma unroll
        for (int ks = 0; ks < 2; ++ks) {
            half8 af[4], bf[4];
            const int ko = ks * 32 + (lane >> 4) * 8;
            const int fr = lane & 15;
            #pragma unroll
            for (int i = 0; i < 4; ++i) af[i] = *(const half8*)&As2[wm + i * 16 + fr][ko];
            #pragma unroll
            for (int i = 0; i < 4; ++i) bf[i] = *(const half8*)&Bs2[wn + i * 16 + fr][ko];
            #pragma unroll
            for (int mf = 0; mf < 4; ++mf)
                #pragma unroll
                for (int nf = 0; nf < 4; ++nf)
                    acc[mf][nf] = __builtin_amdgcn_mfma_f32_16x16x32_f16(
                        af[mf], bf[nf], acc[mf][nf], 0, 0, 0);
        }
    };
    LOADT(0); STORET(); __syncthreads();
    for (int kt = 1; kt < NKT; ++kt) {
        LOADT(kt); COMPUTE(); __syncthreads(); STORET(); __syncthreads();
    }
    COMPUTE();
    const int rb = bm * BM + wm + ((lane >> 4) << 2);
    const int cb = bn * BN + wn + (lane & 15);
    #pragma unroll
    for (int nf = 0; nf < 4; ++nf) {
        const int col = cb + nf * 16;
        const float lb = linb[col];
        #pragma unroll
        for (int mf = 0; mf < 4; ++mf) {
            const int row = rb + mf * 16;
            #pragma unroll
            for (int j = 0; j < 4; ++j)
                out[(size_t)(row + j) * N_DIM + col] = acc[mf][nf][j] + lb;
        }
    }
}

extern "C" void kernel_launch(void* const* d_in, const int* in_sizes, int n_in,
                              void* d_out, int out_size, void* d_ws, size_t ws_size,
                              hipStream_t stream) {
    const float*    x      = (const float*)d_in[0];
    const uint32_t* qw     = (const uint32_t*)d_in[1];
    const float*    scales = (const float*)d_in[2];
    const float*    biases = (const float*)d_in[3];
    const float*    linb   = (const float*)d_in[4];
    float*          out    = (float*)d_out;

    const int M = in_sizes[0] / K_DIM;                 // 8192
    const size_t need = (size_t)M * K_DIM * sizeof(_Float16);
    dim3 grid((M / BM) * (N_DIM / BN));                // 5504

    if (ws_size >= need && (M % BM) == 0) {
        _Float16* xh = (_Float16*)d_ws;
        const size_t nchunk = (size_t)M * K_DIM / 8;   // 4.19M
        cvt_x<<<(unsigned)(nchunk / 256), 256, 0, stream>>>(x, xh);
        qlin_f16<<<grid, 256, 0, stream>>>(xh, qw, scales, biases, linb, out);
    } else {
        qlin_mfma<<<grid, 256, 0, stream>>>(x, qw, scales, biases, linb, out);
    }
}

// Round 4
// 1056.145 us; speedup vs baseline: 1.9939x; 1.0302x over previous
//
#include <hip/hip_runtime.h>
#include <hip/hip_fp16.h>
#include <stdint.h>

#define K_DIM 4096
#define N_DIM 11008
#define WPR   512            // packed int32 words per output row
#define NGRP  32             // quant groups per row

typedef _Float16 half8 __attribute__((ext_vector_type(8)));
typedef float floatx4 __attribute__((ext_vector_type(4)));
union H8 { __half2 h2[4]; half8 v; };

#define GLOAD16(g, l) __builtin_amdgcn_global_load_lds( \
    (const __attribute__((address_space(1))) uint32_t*)(g), \
    (__attribute__((address_space(3))) uint32_t*)(l), 16, 0, 0)

// ---------- pre-pass 1: x f32 -> f16, k-interleaved per 8-chunk (x0,x4,x1,x5,x2,x6,x3,x7)
__global__ __launch_bounds__(256)
void cvt_x(const float* __restrict__ x, _Float16* __restrict__ xh) {
    size_t i = (size_t)blockIdx.x * blockDim.x + threadIdx.x;  // one 8-chunk per thread
    const float4* p = (const float4*)(x + i * 8);
    float4 a = p[0], b = p[1];
    H8 h;
    h.h2[0] = __floats2half2_rn(a.x, b.x);
    h.h2[1] = __floats2half2_rn(a.y, b.y);
    h.h2[2] = __floats2half2_rn(a.z, b.z);
    h.h2[3] = __floats2half2_rn(a.w, b.w);
    *(half8*)(xh + i * 8) = h.v;
}

// ---------- pre-pass 2: dequant W -> f16, same per-8-chunk interleave (c0,c4,c1,c5,...)
__global__ __launch_bounds__(256)
void deq_w(const uint32_t* __restrict__ qw, const float* __restrict__ scales,
           const float* __restrict__ biases, _Float16* __restrict__ wh) {
    const size_t i = (size_t)blockIdx.x * 256 + threadIdx.x;   // one uint4 (4 words)
    const int row = (int)(i >> 7);            // 128 uint4 per row
    const int w0  = ((int)i & 127) << 2;      // word offset in row (4-aligned, never crosses group)
    const uint4 q = ((const uint4*)qw)[i];
    const int g = w0 >> 4;                    // 16 words per 128-k group
    const __half2 s2 = __half2half2(__float2half(scales[(size_t)row * NGRP + g]));
    const __half2 b2 = __half2half2(__float2half(biases[(size_t)row * NGRP + g]));
    const __half2 c1024 = __float2half2_rn(1024.0f);
    _Float16* o = wh + (size_t)row * K_DIM + w0 * 8;
    const uint32_t uws[4] = {q.x, q.y, q.z, q.w};
    #pragma unroll
    for (int wi = 0; wi < 4; ++wi) {
        const uint32_t u = uws[wi];
        H8 h;
        #pragma unroll
        for (int p = 0; p < 4; ++p) {
            const uint32_t v = ((u >> (4 * p)) & 0x000F000Fu) | 0x64006400u;
            const __half2 q2 = __hsub2(__builtin_bit_cast(__half2, v), c1024);
            h.h2[p] = __hfma2(s2, q2, b2);
        }
        *(half8*)(o + wi * 8) = h.v;
    }
}

// ---------- main GEMM: 256x256 tile, BK=32, 8 waves, 4 LDS buffers, counted vmcnt
#define BM8 256
#define BN8 256
#define BK8 32
#define NKT8 (K_DIM / BK8)   // 128

__global__ __launch_bounds__(512, 2)
void qlin8(const _Float16* __restrict__ xh, const _Float16* __restrict__ wh,
           const float* __restrict__ linb, float* __restrict__ out)
{
    __shared__ _Float16 As[4][BM8 * BK8];   // 4 x 16 KB
    __shared__ _Float16 Bs[4][BN8 * BK8];   // 4 x 16 KB   -> 128 KB total

    // XCD-bijective swizzle (grid 1376 = 8*172): consecutive-on-XCD share A panel
    const int nwg = gridDim.x;
    int b = blockIdx.x;
    if ((nwg & 7) == 0) b = (b & 7) * (nwg >> 3) + (b >> 3);
    const int NBN = N_DIM / BN8;            // 43
    const int bn = b % NBN;
    const int bm = b / NBN;

    const int tid  = threadIdx.x;
    const int lane = tid & 63;
    const int wid  = tid >> 6;              // 0..7
    const int wr   = wid >> 2;              // 0..1 -> 128-row half
    const int wc   = wid & 3;               // 0..3 -> 64-col slice
    const int fr   = lane & 15;
    const int kq   = lane >> 4;             // 0..3 k-chunk
    const int kc   = ((kq ^ ((fr >> 1) & 3)) << 3);  // swizzled chunk offset (halves)

    // staging: thread t -> 16B unit t (rows 0-127) and t+512 (rows 128-255)
    const int r0 = tid >> 2;                // 0..127
    const int c0 = tid & 3;
    const int cs = (c0 ^ ((r0 >> 1) & 3)) << 3;      // pre-swizzled source chunk (halves)
    const _Float16* aS = xh + (size_t)(bm * BM8 + r0) * K_DIM + cs;
    const _Float16* bS = wh + (size_t)(bn * BN8 + r0) * K_DIM + cs;
    const int ldst = wid << 9;              // wave-uniform LDS base (halves)

    floatx4 acc[8][4] = {};

    auto STAGE = [&](int buf, int kt) {
        const _Float16* pa = aS + kt * BK8;
        const _Float16* pb = bS + kt * BK8;
        GLOAD16(pa,                         &As[buf][ldst]);
        GLOAD16(pa + (size_t)128 * K_DIM,   &As[buf][ldst + 4096]);
        GLOAD16(pb,                         &Bs[buf][ldst]);
        GLOAD16(pb + (size_t)128 * K_DIM,   &Bs[buf][ldst + 4096]);
    };

    const int arow = (wr * 128 + fr) * BK8 + kc;
    const int brow = (wc * 64  + fr) * BK8 + kc;

    auto BODY = [&](int kt, bool stage, int vm) {
        const _Float16* Ab = &As[kt & 3][0];
        const _Float16* Bb = &Bs[kt & 3][0];
        if (stage) STAGE((kt + 3) & 3, kt + 3);
        half8 a[8], bq[4];
        #pragma unroll
        for (int mf = 0; mf < 8; ++mf)
            a[mf] = *(const half8*)(Ab + arow + mf * (16 * BK8));
        #pragma unroll
        for (int nf = 0; nf < 4; ++nf)
            bq[nf] = *(const half8*)(Bb + brow + nf * (16 * BK8));
        __builtin_amdgcn_s_setprio(1);
        #pragma unroll
        for (int mf = 0; mf < 8; ++mf)
            #pragma unroll
            for (int nf = 0; nf < 4; ++nf)
                acc[mf][nf] = __builtin_amdgcn_mfma_f32_16x16x32_f16(
                    a[mf], bq[nf], acc[mf][nf], 0, 0, 0);
        __builtin_amdgcn_s_setprio(0);
        __builtin_amdgcn_sched_barrier(0);
        if (vm == 8)      asm volatile("s_waitcnt vmcnt(8)" ::: "memory");
        else if (vm == 4) asm volatile("s_waitcnt vmcnt(4)" ::: "memory");
        else if (vm == 0) asm volatile("s_waitcnt vmcnt(0)" ::: "memory");
        if (vm >= 0) __builtin_amdgcn_s_barrier();
        __builtin_amdgcn_sched_barrier(0);
    };

    // prologue: stage tiles 0,1,2; commit tile 0 (vmcnt(8) leaves tiles 1,2 in flight)
    STAGE(0, 0); STAGE(1, 1); STAGE(2, 2);
    asm volatile("s_waitcnt vmcnt(8)" ::: "memory");
    __builtin_amdgcn_s_barrier();
    __builtin_amdgcn_sched_barrier(0);

    // steady state: body kt consumes buf[kt&3], issues kt+3, retires kt+1 (vmcnt(8))
    for (int kt = 0; kt < NKT8 - 3; ++kt) BODY(kt, true, 8);
    BODY(NKT8 - 3, false, 4);
    BODY(NKT8 - 2, false, 0);
    BODY(NKT8 - 1, false, -1);

    // epilogue: C/D layout col = lane&15, row = (lane>>4)*4 + j
    const int rb = bm * BM8 + wr * 128 + (kq << 2);
    const int cb = bn * BN8 + wc * 64 + fr;
    #pragma unroll
    for (int nf = 0; nf < 4; ++nf) {
        const int col = cb + nf * 16;
        const float lb = linb[col];
        #pragma unroll
        for (int mf = 0; mf < 8; ++mf) {
            const int row = rb + mf * 16;
            #pragma unroll
            for (int j = 0; j < 4; ++j)
                out[(size_t)(row + j) * N_DIM + col] = acc[mf][nf][j] + lb;
        }
    }
}

// ---------- fallback (round-3 verified): fused-dequant 128x128 2-phase ----------
#define BM 128
#define BN 128
#define BK 64
#define NKT (K_DIM / BK)

__global__ __launch_bounds__(256, 2)
void qlin_f16(const _Float16* __restrict__ xh,
              const uint32_t* __restrict__ qw,
              const float* __restrict__ scales,
              const float* __restrict__ biases,
              const float* __restrict__ linb,
              float* __restrict__ out)
{
    __shared__ _Float16 Asf[2][BM * BK];
    __shared__ _Float16 Bsf[2][BN * BK];

    const int NBN = N_DIM / BN;
    const int bn = blockIdx.x % NBN;
    const int bm = blockIdx.x / NBN;
    const int tid  = threadIdx.x;
    const int lane = tid & 63;
    const int wv   = tid >> 6;
    const int wm   = (wv >> 1) * 64;
    const int wn   = (wv & 1) * 64;

    const int arow = wv * 32 + (lane >> 3);
    const int acs  = ((lane & 7) ^ ((lane >> 3) & 7)) * 8;
    const _Float16* aSrc = xh + (size_t)(bm * BM + arow) * K_DIM + acs;

    const int srow = tid >> 1;
    const int bsel = tid & 1;
    const uint32_t* qB = qw + (size_t)(bn * BN + srow) * WPR + bsel * 4;
    const float*    sB = scales + (size_t)(bn * BN + srow) * NGRP;
    const float*    bB = biases + (size_t)(bn * BN + srow) * NGRP;
    const int bwbase = srow * BK;
    const int bswz   = srow & 7;

    floatx4 acc[4][4] = {};
    uint4 q0, q1; float s0, b0, s1, b1;

    auto LOADB = [&](uint4& qr, float& s, float& bb, int kt) {
        qr = *(const uint4*)(qB + kt * 8);
        s = sB[kt >> 1]; bb = bB[kt >> 1];
    };
    auto GLOADA = [&](int buf, int kt) {
        const _Float16* sp = aSrc + (size_t)kt * BK;
        #pragma unroll
        for (int j = 0; j < 4; ++j)
            GLOAD16(sp + (size_t)j * 8 * K_DIM, &Asf[buf][wv * 2048 + j * 512]);
    };
    auto DEQ = [&](const uint4& qr, float sf, float bf, int buf) {
        const __half2 s2 = __half2half2(__float2half(sf));
        const __half2 b2 = __half2half2(__float2half(bf));
        const __half2 c1024 = __float2half2_rn(1024.0f);
        const uint32_t uws[4] = {qr.x, qr.y, qr.z, qr.w};
        #pragma unroll
        for (int wi = 0; wi < 4; ++wi) {
            const uint32_t u = uws[wi];
            H8 h;
            #pragma unroll
            for (int p = 0; p < 4; ++p) {
                const uint32_t v = ((u >> (4 * p)) & 0x000F000Fu) | 0x64006400u;
                const __half2 q2 = __hsub2(__builtin_bit_cast(__half2, v), c1024);
                h.h2[p] = __hfma2(s2, q2, b2);
            }
            const int c = bsel * 4 + wi;
            *(half8*)&Bsf[buf][bwbase + ((c ^ bswz) * 8)] = h.v;
        }
    };
    const int fr = lane & 15;
    const int kq = lane >> 4;
    auto COMPUTE = [&](int buf) {
        const _Float16* Ab = &Asf[buf][0];
        const _Float16* Bb = &Bsf[buf][0];
        #pragma unroll
        for (int ks = 0; ks < 2; ++ks) {
            half8 af[4], bf[4];
            const int csx = ks * 4 + kq;
            #pragma unroll
            for (int i = 0; i < 4; ++i) {
                const int r = wm + i * 16 + fr;
                af[i] = *(const half8*)(Ab + r * BK + ((csx ^ (r & 7)) * 8));
            }
            #pragma unroll
            for (int i = 0; i < 4; ++i) {
                const int r = wn + i * 16 + fr;
                bf[i] = *(const half8*)(Bb + r * BK + ((csx ^ (r & 7)) * 8));
            }
            #pragma unroll
            for (int mf = 0; mf < 4; ++mf)
                #pragma unroll
                for (int nf = 0; nf < 4; ++nf)
                    acc[mf][nf] = __builtin_amdgcn_mfma_f32_16x16x32_f16(
                        af[mf], bf[nf], acc[mf][nf], 0, 0, 0);
        }
    };

    LOADB(q0, s0, b0, 0);
    GLOADA(0, 0);
    DEQ(q0, s0, b0, 0);
    LOADB(q0, s0, b0, 1);
    __syncthreads();
    for (int kt = 0; kt < NKT; kt += 2) {
        GLOADA(1, kt + 1);
        if (kt + 2 < NKT) LOADB(q1, s1, b1, kt + 2);
        DEQ(q0, s0, b0, 1);
        COMPUTE(0);
        __syncthreads();
        if (kt + 2 < NKT) {
            GLOADA(0, kt + 2);
            if (kt + 3 < NKT) LOADB(q0, s0, b0, kt + 3);
            DEQ(q1, s1, b1, 0);
        }
        COMPUTE(1);
        if (kt + 2 < NKT) __syncthreads();
    }
    const int rb = bm * BM + wm + ((lane >> 4) << 2);
    const int cb = bn * BN + wn + (lane & 15);
    #pragma unroll
    for (int nf = 0; nf < 4; ++nf) {
        const int col = cb + nf * 16;
        const float lb = linb[col];
        #pragma unroll
        for (int mf = 0; mf < 4; ++mf) {
            const int row = rb + mf * 16;
            #pragma unroll
            for (int j = 0; j < 4; ++j)
                out[(size_t)(row + j) * N_DIM + col] = acc[mf][nf][j] + lb;
        }
    }
}

extern "C" void kernel_launch(void* const* d_in, const int* in_sizes, int n_in,
                              void* d_out, int out_size, void* d_ws, size_t ws_size,
                              hipStream_t stream) {
    const float*    x      = (const float*)d_in[0];
    const uint32_t* qw     = (const uint32_t*)d_in[1];
    const float*    scales = (const float*)d_in[2];
    const float*    biases = (const float*)d_in[3];
    const float*    linb   = (const float*)d_in[4];
    float*          out    = (float*)d_out;

    const int M = in_sizes[0] / K_DIM;                      // 8192
    const size_t needX = (size_t)M * K_DIM * sizeof(_Float16);
    const size_t needW = (size_t)N_DIM * K_DIM * sizeof(_Float16);

    if (ws_size >= needX + needW && (M % 256) == 0) {
        _Float16* xh = (_Float16*)d_ws;
        _Float16* wh = xh + (size_t)M * K_DIM;
        cvt_x<<<(unsigned)((size_t)M * K_DIM / 8 / 256), 256, 0, stream>>>(x, xh);
        deq_w<<<(unsigned)((size_t)N_DIM * WPR / 4 / 256), 256, 0, stream>>>(qw, scales, biases, wh);
        dim3 grid((M / BM8) * (N_DIM / BN8));               // 32*43 = 1376
        qlin8<<<grid, 512, 0, stream>>>(xh, wh, linb, out);
    } else if (ws_size >= needX && (M % BM) == 0) {
        _Float16* xh = (_Float16*)d_ws;
        cvt_x<<<(unsigned)((size_t)M * K_DIM / 8 / 256), 256, 0, stream>>>(x, xh);
        dim3 grid((M / BM) * (N_DIM / BN));
        qlin_f16<<<grid, 256, 0, stream>>>(xh, qw, scales, biases, linb, out);
    }
}

// Round 5
// 1010.077 us; speedup vs baseline: 2.0849x; 1.0456x over previous
//
#include <hip/hip_runtime.h>
#include <hip/hip_fp16.h>
#include <stdint.h>

#define K_DIM 4096
#define N_DIM 11008
#define WPR   512            // packed int32 words per output row
#define NGRP  32             // quant groups per row

typedef _Float16 half8 __attribute__((ext_vector_type(8)));
typedef float floatx4 __attribute__((ext_vector_type(4)));
union H8 { __half2 h2[4]; half8 v; };

#define GLOAD16(g, l) __builtin_amdgcn_global_load_lds( \
    (const __attribute__((address_space(1))) uint32_t*)(g), \
    (__attribute__((address_space(3))) uint32_t*)(l), 16, 0, 0)

// ---------- pre-pass 1: x f32 -> f16, k-interleaved per 8-chunk (x0,x4,x1,x5,x2,x6,x3,x7)
__global__ __launch_bounds__(256)
void cvt_x(const float* __restrict__ x, _Float16* __restrict__ xh) {
    size_t i = (size_t)blockIdx.x * blockDim.x + threadIdx.x;  // one 8-chunk per thread
    const float4* p = (const float4*)(x + i * 8);
    float4 a = p[0], b = p[1];
    H8 h;
    h.h2[0] = __floats2half2_rn(a.x, b.x);
    h.h2[1] = __floats2half2_rn(a.y, b.y);
    h.h2[2] = __floats2half2_rn(a.z, b.z);
    h.h2[3] = __floats2half2_rn(a.w, b.w);
    *(half8*)(xh + i * 8) = h.v;
}

// ---------- pre-pass 2: dequant W -> f16, same per-8-chunk interleave (c0,c4,c1,c5,...)
__global__ __launch_bounds__(256)
void deq_w(const uint32_t* __restrict__ qw, const float* __restrict__ scales,
           const float* __restrict__ biases, _Float16* __restrict__ wh) {
    const size_t i = (size_t)blockIdx.x * 256 + threadIdx.x;   // one uint4 (4 words)
    const int row = (int)(i >> 7);
    const int w0  = ((int)i & 127) << 2;
    const uint4 q = ((const uint4*)qw)[i];
    const int g = w0 >> 4;
    const __half2 s2 = __half2half2(__float2half(scales[(size_t)row * NGRP + g]));
    const __half2 b2 = __half2half2(__float2half(biases[(size_t)row * NGRP + g]));
    const __half2 c1024 = __float2half2_rn(1024.0f);
    _Float16* o = wh + (size_t)row * K_DIM + w0 * 8;
    const uint32_t uws[4] = {q.x, q.y, q.z, q.w};
    #pragma unroll
    for (int wi = 0; wi < 4; ++wi) {
        const uint32_t u = uws[wi];
        H8 h;
        #pragma unroll
        for (int p = 0; p < 4; ++p) {
            const uint32_t v = ((u >> (4 * p)) & 0x000F000Fu) | 0x64006400u;
            const __half2 q2 = __hsub2(__builtin_bit_cast(__half2, v), c1024);
            h.h2[p] = __hfma2(s2, q2, b2);
        }
        *(half8*)(o + wi * 8) = h.v;
    }
}

// ---------- main GEMM: 256x256 tile, BK=32, 8 waves, 4 LDS buffers,
// ---------- phase-split bodies (T3) + counted vmcnt (T4) + setprio (T5)
#define BM8 256
#define BN8 256
#define BK8 32
#define NKT8 (K_DIM / BK8)   // 128

__global__ __launch_bounds__(512, 2)
void qlin8(const _Float16* __restrict__ xh, const _Float16* __restrict__ wh,
           const float* __restrict__ linb, float* __restrict__ out)
{
    __shared__ _Float16 As[4][BM8 * BK8];   // 4 x 16 KB
    __shared__ _Float16 Bs[4][BN8 * BK8];   // 4 x 16 KB   -> 128 KB total

    const int nwg = gridDim.x;
    int b = blockIdx.x;
    if ((nwg & 7) == 0) b = (b & 7) * (nwg >> 3) + (b >> 3);  // XCD-bijective swizzle
    const int NBN = N_DIM / BN8;            // 43
    const int bn = b % NBN;
    const int bm = b / NBN;

    const int tid  = threadIdx.x;
    const int lane = tid & 63;
    const int wid  = tid >> 6;
    const int wr   = wid >> 2;              // 0..1 -> 128-row half
    const int wc   = wid & 3;               // 0..3 -> 64-col slice
    const int fr   = lane & 15;
    const int kq   = lane >> 4;
    const int kc   = ((kq ^ ((fr >> 1) & 3)) << 3);  // swizzled chunk offset (halves)

    // staging: thread t -> 16B unit t (rows 0-127) and t+512 (rows 128-255)
    const int r0 = tid >> 2;
    const int c0 = tid & 3;
    const int cs = (c0 ^ ((r0 >> 1) & 3)) << 3;      // pre-swizzled source chunk
    const _Float16* aS = xh + (size_t)(bm * BM8 + r0) * K_DIM + cs;
    const _Float16* bS = wh + (size_t)(bn * BN8 + r0) * K_DIM + cs;
    const int ldst = wid << 9;

    floatx4 acc[8][4] = {};
    half8 a[4], bq[4];

    const int arow = (wr * 128 + fr) * BK8 + kc;
    const int brow = (wc * 64  + fr) * BK8 + kc;

    auto STAGE_A = [&](int kt) {            // half 1 of tile kt's staging
        const _Float16* pa = aS + kt * BK8;
        const int buf = kt & 3;
        GLOAD16(pa,                       &As[buf][ldst]);
        GLOAD16(pa + (size_t)128 * K_DIM, &As[buf][ldst + 4096]);
    };
    auto STAGE_B = [&](int kt) {            // half 2
        const _Float16* pb = bS + kt * BK8;
        const int buf = kt & 3;
        GLOAD16(pb,                       &Bs[buf][ldst]);
        GLOAD16(pb + (size_t)128 * K_DIM, &Bs[buf][ldst + 4096]);
    };

    // Phase A: ds_read {A mf0-3, B all} || stage A-half(kt+3); bar; lgkm0; 16 MFMA; bar
    auto PHA = [&](int kt, bool stage) {
        const _Float16* Ab = &As[kt & 3][0];
        const _Float16* Bb = &Bs[kt & 3][0];
        #pragma unroll
        for (int nf = 0; nf < 4; ++nf)
            bq[nf] = *(const half8*)(Bb + brow + nf * (16 * BK8));
        #pragma unroll
        for (int mf = 0; mf < 4; ++mf)
            a[mf] = *(const half8*)(Ab + arow + mf * (16 * BK8));
        if (stage) STAGE_A(kt + 3);
        __builtin_amdgcn_s_barrier();
        asm volatile("s_waitcnt lgkmcnt(0)" ::: "memory");
        __builtin_amdgcn_sched_barrier(0);
        __builtin_amdgcn_s_setprio(1);
        #pragma unroll
        for (int mf = 0; mf < 4; ++mf)
            #pragma unroll
            for (int nf = 0; nf < 4; ++nf)
                acc[mf][nf] = __builtin_amdgcn_mfma_f32_16x16x32_f16(
                    a[mf], bq[nf], acc[mf][nf], 0, 0, 0);
        __builtin_amdgcn_s_setprio(0);
        __builtin_amdgcn_sched_barrier(0);
        __builtin_amdgcn_s_barrier();
    };

    // Phase B: ds_read {A mf4-7} (B reused) || stage B-half(kt+3); vmcnt(N); bar;
    //          lgkm0; 16 MFMA; bar. vmcnt retires tile kt+1's 4 wave-loads.
    auto PHB = [&](int kt, bool stage, int vm) {
        const _Float16* Ab = &As[kt & 3][0];
        #pragma unroll
        for (int mf = 0; mf < 4; ++mf)
            a[mf] = *(const half8*)(Ab + arow + (mf + 4) * (16 * BK8));
        if (stage) STAGE_B(kt + 3);
        if (vm == 8)      asm volatile("s_waitcnt vmcnt(8)" ::: "memory");
        else if (vm == 4) asm volatile("s_waitcnt vmcnt(4)" ::: "memory");
        else if (vm == 0) asm volatile("s_waitcnt vmcnt(0)" ::: "memory");
        __builtin_amdgcn_s_barrier();
        asm volatile("s_waitcnt lgkmcnt(0)" ::: "memory");
        __builtin_amdgcn_sched_barrier(0);
        __builtin_amdgcn_s_setprio(1);
        #pragma unroll
        for (int mf = 0; mf < 4; ++mf)
            #pragma unroll
            for (int nf = 0; nf < 4; ++nf)
                acc[mf + 4][nf] = __builtin_amdgcn_mfma_f32_16x16x32_f16(
                    a[mf], bq[nf], acc[mf + 4][nf], 0, 0, 0);
        __builtin_amdgcn_s_setprio(0);
        __builtin_amdgcn_sched_barrier(0);
        if (vm >= 0) __builtin_amdgcn_s_barrier();
    };

    // prologue: stage tiles 0,1,2 (12 wave-loads); commit tile 0 (vmcnt(8))
    STAGE_A(0); STAGE_B(0);
    STAGE_A(1); STAGE_B(1);
    STAGE_A(2); STAGE_B(2);
    asm volatile("s_waitcnt vmcnt(8)" ::: "memory");
    __builtin_amdgcn_s_barrier();
    __builtin_amdgcn_sched_barrier(0);

    for (int kt = 0; kt < NKT8 - 3; ++kt) { PHA(kt, true); PHB(kt, true, 8); }
    PHA(NKT8 - 3, false); PHB(NKT8 - 3, false, 4);
    PHA(NKT8 - 2, false); PHB(NKT8 - 2, false, 0);
    PHA(NKT8 - 1, false); PHB(NKT8 - 1, false, -1);

    // epilogue: C/D layout col = lane&15, row = (lane>>4)*4 + j
    const int rb = bm * BM8 + wr * 128 + (kq << 2);
    const int cb = bn * BN8 + wc * 64 + fr;
    #pragma unroll
    for (int nf = 0; nf < 4; ++nf) {
        const int col = cb + nf * 16;
        const float lb = linb[col];
        #pragma unroll
        for (int mf = 0; mf < 8; ++mf) {
            const int row = rb + mf * 16;
            #pragma unroll
            for (int j = 0; j < 4; ++j)
                out[(size_t)(row + j) * N_DIM + col] = acc[mf][nf][j] + lb;
        }
    }
}

// ---------- fallback (round-3 verified): fused-dequant 128x128 2-phase ----------
#define BM 128
#define BN 128
#define BK 64
#define NKT (K_DIM / BK)

__global__ __launch_bounds__(256, 2)
void qlin_f16(const _Float16* __restrict__ xh,
              const uint32_t* __restrict__ qw,
              const float* __restrict__ scales,
              const float* __restrict__ biases,
              const float* __restrict__ linb,
              float* __restrict__ out)
{
    __shared__ _Float16 Asf[2][BM * BK];
    __shared__ _Float16 Bsf[2][BN * BK];

    const int NBN = N_DIM / BN;
    const int bn = blockIdx.x % NBN;
    const int bm = blockIdx.x / NBN;
    const int tid  = threadIdx.x;
    const int lane = tid & 63;
    const int wv   = tid >> 6;
    const int wm   = (wv >> 1) * 64;
    const int wn   = (wv & 1) * 64;

    const int arow = wv * 32 + (lane >> 3);
    const int acs  = ((lane & 7) ^ ((lane >> 3) & 7)) * 8;
    const _Float16* aSrc = xh + (size_t)(bm * BM + arow) * K_DIM + acs;

    const int srow = tid >> 1;
    const int bsel = tid & 1;
    const uint32_t* qB = qw + (size_t)(bn * BN + srow) * WPR + bsel * 4;
    const float*    sB = scales + (size_t)(bn * BN + srow) * NGRP;
    const float*    bB = biases + (size_t)(bn * BN + srow) * NGRP;
    const int bwbase = srow * BK;
    const int bswz   = srow & 7;

    floatx4 acc[4][4] = {};
    uint4 q0, q1; float s0, b0, s1, b1;

    auto LOADB = [&](uint4& qr, float& s, float& bb, int kt) {
        qr = *(const uint4*)(qB + kt * 8);
        s = sB[kt >> 1]; bb = bB[kt >> 1];
    };
    auto GLOADA = [&](int buf, int kt) {
        const _Float16* sp = aSrc + (size_t)kt * BK;
        #pragma unroll
        for (int j = 0; j < 4; ++j)
            GLOAD16(sp + (size_t)j * 8 * K_DIM, &Asf[buf][wv * 2048 + j * 512]);
    };
    auto DEQ = [&](const uint4& qr, float sf, float bf, int buf) {
        const __half2 s2 = __half2half2(__float2half(sf));
        const __half2 b2 = __half2half2(__float2half(bf));
        const __half2 c1024 = __float2half2_rn(1024.0f);
        const uint32_t uws[4] = {qr.x, qr.y, qr.z, qr.w};
        #pragma unroll
        for (int wi = 0; wi < 4; ++wi) {
            const uint32_t u = uws[wi];
            H8 h;
            #pragma unroll
            for (int p = 0; p < 4; ++p) {
                const uint32_t v = ((u >> (4 * p)) & 0x000F000Fu) | 0x64006400u;
                const __half2 q2 = __hsub2(__builtin_bit_cast(__half2, v), c1024);
                h.h2[p] = __hfma2(s2, q2, b2);
            }
            const int c = bsel * 4 + wi;
            *(half8*)&Bsf[buf][bwbase + ((c ^ bswz) * 8)] = h.v;
        }
    };
    const int fr = lane & 15;
    const int kq = lane >> 4;
    auto COMPUTE = [&](int buf) {
        const _Float16* Ab = &Asf[buf][0];
        const _Float16* Bb = &Bsf[buf][0];
        #pragma unroll
        for (int ks = 0; ks < 2; ++ks) {
            half8 af[4], bf[4];
            const int csx = ks * 4 + kq;
            #pragma unroll
            for (int i = 0; i < 4; ++i) {
                const int r = wm + i * 16 + fr;
                af[i] = *(const half8*)(Ab + r * BK + ((csx ^ (r & 7)) * 8));
            }
            #pragma unroll
            for (int i = 0; i < 4; ++i) {
                const int r = wn + i * 16 + fr;
                bf[i] = *(const half8*)(Bb + r * BK + ((csx ^ (r & 7)) * 8));
            }
            #pragma unroll
            for (int mf = 0; mf < 4; ++mf)
                #pragma unroll
                for (int nf = 0; nf < 4; ++nf)
                    acc[mf][nf] = __builtin_amdgcn_mfma_f32_16x16x32_f16(
                        af[mf], bf[nf], acc[mf][nf], 0, 0, 0);
        }
    };

    LOADB(q0, s0, b0, 0);
    GLOADA(0, 0);
    DEQ(q0, s0, b0, 0);
    LOADB(q0, s0, b0, 1);
    __syncthreads();
    for (int kt = 0; kt < NKT; kt += 2) {
        GLOADA(1, kt + 1);
        if (kt + 2 < NKT) LOADB(q1, s1, b1, kt + 2);
        DEQ(q0, s0, b0, 1);
        COMPUTE(0);
        __syncthreads();
        if (kt + 2 < NKT) {
            GLOADA(0, kt + 2);
            if (kt + 3 < NKT) LOADB(q0, s0, b0, kt + 3);
            DEQ(q1, s1, b1, 0);
        }
        COMPUTE(1);
        if (kt + 2 < NKT) __syncthreads();
    }
    const int rb = bm * BM + wm + ((lane >> 4) << 2);
    const int cb = bn * BN + wn + (lane & 15);
    #pragma unroll
    for (int nf = 0; nf < 4; ++nf) {
        const int col = cb + nf * 16;
        const float lb = linb[col];
        #pragma unroll
        for (int mf = 0; mf < 4; ++mf) {
            const int row = rb + mf * 16;
            #pragma unroll
            for (int j = 0; j < 4; ++j)
                out[(size_t)(row + j) * N_DIM + col] = acc[mf][nf][j] + lb;
        }
    }
}

extern "C" void kernel_launch(void* const* d_in, const int* in_sizes, int n_in,
                              void* d_out, int out_size, void* d_ws, size_t ws_size,
                              hipStream_t stream) {
    const float*    x      = (const float*)d_in[0];
    const uint32_t* qw     = (const uint32_t*)d_in[1];
    const float*    scales = (const float*)d_in[2];
    const float*    biases = (const float*)d_in[3];
    const float*    linb   = (const float*)d_in[4];
    float*          out    = (float*)d_out;

    const int M = in_sizes[0] / K_DIM;                      // 8192
    const size_t needX = (size_t)M * K_DIM * sizeof(_Float16);
    const size_t needW = (size_t)N_DIM * K_DIM * sizeof(_Float16);

    if (ws_size >= needX + needW && (M % 256) == 0) {
        _Float16* xh = (_Float16*)d_ws;
        _Float16* wh = xh + (size_t)M * K_DIM;
        cvt_x<<<(unsigned)((size_t)M * K_DIM / 8 / 256), 256, 0, stream>>>(x, xh);
        deq_w<<<(unsigned)((size_t)N_DIM * WPR / 4 / 256), 256, 0, stream>>>(qw, scales, biases, wh);
        dim3 grid((M / BM8) * (N_DIM / BN8));               // 32*43 = 1376
        qlin8<<<grid, 512, 0, stream>>>(xh, wh, linb, out);
    } else if (ws_size >= needX && (M % BM) == 0) {
        _Float16* xh = (_Float16*)d_ws;
        cvt_x<<<(unsigned)((size_t)M * K_DIM / 8 / 256), 256, 0, stream>>>(x, xh);
        dim3 grid((M / BM) * (N_DIM / BN));
        qlin_f16<<<grid, 256, 0, stream>>>(xh, qw, scales, biases, linb, out);
    }
}

// Round 6
// 939.356 us; speedup vs baseline: 2.2418x; 1.0753x over previous
//
#include <hip/hip_runtime.h>
#include <hip/hip_fp16.h>
#include <stdint.h>

#define K_DIM 4096
#define N_DIM 11008
#define WPR   512            // packed int32 words per output row
#define NGRP  32             // quant groups per row

typedef _Float16 half8 __attribute__((ext_vector_type(8)));
typedef float floatx16 __attribute__((ext_vector_type(16)));
typedef float floatx4 __attribute__((ext_vector_type(4)));
union H8 { __half2 h2[4]; half8 v; };

#define GLOAD16(g, l) __builtin_amdgcn_global_load_lds( \
    (const __attribute__((address_space(1))) uint32_t*)(g), \
    (__attribute__((address_space(3))) uint32_t*)(l), 16, 0, 0)

// ============ fragment-major layout for mfma_f32_32x32x16 ============
// 16B unit u = blk32*16384 + (kh>>1)*64 + (kh&1)*32 + r
//   blk32 = row/32 (or col/32), kh = k/8 (0..511), r = row&31
// halves within a unit: interleaved (e0,e4,e1,e5,e2,e6,e3,e7) of k-chunk kh
// (A and B share the permutation -> dot products unaffected).
// Wave fragment load for (blk32, kstep16 s): lane l reads unit
//   blk32*16384 + kt*128 + s*64 + l   -> lane-contiguous, coalesced.

// ---------- pre-pass 1: x f32 -> f16 fragment-major
__global__ __launch_bounds__(256)
void cvt_x2(const float* __restrict__ x, _Float16* __restrict__ xh) {
    const size_t i = (size_t)blockIdx.x * 256 + threadIdx.x;
    const int r  = (int)i & 31;
    const int kh = ((int)(i >> 5)) & 511;
    const int mb = (int)(i >> 14);
    const float4* p = (const float4*)(x + ((size_t)mb * 32 + r) * K_DIM + kh * 8);
    float4 a = p[0], b = p[1];
    H8 h;
    h.h2[0] = __floats2half2_rn(a.x, b.x);
    h.h2[1] = __floats2half2_rn(a.y, b.y);
    h.h2[2] = __floats2half2_rn(a.z, b.z);
    h.h2[3] = __floats2half2_rn(a.w, b.w);
    const size_t u = (size_t)mb * 16384 + (size_t)((kh >> 1) * 64 + (kh & 1) * 32 + r);
    *(half8*)(xh + u * 8) = h.v;
}

// ---------- pre-pass 2: dequant W -> f16 fragment-major
__global__ __launch_bounds__(256)
void deq_w2(const uint32_t* __restrict__ qw, const float* __restrict__ scales,
            const float* __restrict__ biases, _Float16* __restrict__ wh) {
    const size_t i = (size_t)blockIdx.x * 256 + threadIdx.x;
    const int c  = (int)i & 31;
    const int w  = ((int)(i >> 5)) & 511;
    const int nb = (int)(i >> 14);
    const int row = nb * 32 + c;
    const uint32_t u = qw[(size_t)row * WPR + w];
    const int g = w >> 4;
    const __half2 s2 = __half2half2(__float2half(scales[(size_t)row * NGRP + g]));
    const __half2 b2 = __half2half2(__float2half(biases[(size_t)row * NGRP + g]));
    const __half2 c1024 = __float2half2_rn(1024.0f);
    H8 h;
    #pragma unroll
    for (int p = 0; p < 4; ++p) {
        const uint32_t v = ((u >> (4 * p)) & 0x000F000Fu) | 0x64006400u;
        const __half2 q2 = __hsub2(__builtin_bit_cast(__half2, v), c1024);
        h.h2[p] = __hfma2(s2, q2, b2);
    }
    const size_t uo = (size_t)nb * 16384 + (size_t)((w >> 1) * 64 + (w & 1) * 32 + c);
    *(half8*)(wh + uo * 8) = h.v;
}

// ---------- main GEMM: 256x256 tile, BK=32, 8 waves, 32x32x16 MFMA.
// A: LDS 4-buffer via global_load_lds (fragment-major -> linear, no swizzle).
// B: direct global->reg, coalesced fragment loads, double-buffered.
// ONE barrier + one counted vmcnt(6) per K-tile at body end.
__global__ __launch_bounds__(512, 2)
void qlin9(const _Float16* __restrict__ xh, const _Float16* __restrict__ wh,
           const float* __restrict__ linb, float* __restrict__ out)
{
    __shared__ _Float16 As[4][8192];    // 4 x 16 KB = 64 KB

    const int nwg = gridDim.x;
    int b = blockIdx.x;
    if ((nwg & 7) == 0) b = (b & 7) * (nwg >> 3) + (b >> 3);  // XCD swizzle
    const int NBN = N_DIM / 256;        // 43
    const int bn = b % NBN;
    const int bm = b / NBN;

    const int tid  = threadIdx.x;
    const int lane = tid & 63;
    const int wid  = tid >> 6;
    const int wr   = wid >> 2;          // 0..1 -> 128-row half
    const int wc   = wid & 3;           // 0..3 -> 64-col slice

    // A staging: thread t stages LDS units t and t+512 of the buffer.
    // LDS unit q holds global unit (bm*8 + (q>>7))*16384 + kt*128 + (q&127).
    const _Float16* aS0 = xh + ((size_t)(bm * 8 + (tid >> 7)) * 16384 + (size_t)(tid & 127)) * 8;
    const _Float16* aS1 = aS0 + (size_t)4 * 16384 * 8;
    const int ld0 = tid * 8;
    const int ld1 = (tid + 512) * 8;

    // B bases: wave's two 32-col blocks
    const _Float16* bB0 = wh + ((size_t)(bn * 8 + wc * 2) * 16384 + (size_t)lane) * 8;
    const _Float16* bB1 = bB0 + (size_t)16384 * 8;

    floatx16 acc[4][2] = {};
    half8 b0[4], b1[4];

    auto STAGE = [&](int kt) {
        const int k = (kt < 128) ? kt : 0;          // clamped tail (harmless)
        GLOAD16(aS0 + (size_t)k * 1024, &As[kt & 3][ld0]);
        GLOAD16(aS1 + (size_t)k * 1024, &As[kt & 3][ld1]);
    };
    auto LOADB = [&](half8* bq, int kt) {           // bq[j*2+s]
        const int k = (kt < 128) ? kt : 0;
        const _Float16* p0 = bB0 + (size_t)k * 1024;
        const _Float16* p1 = bB1 + (size_t)k * 1024;
        bq[0] = *(const half8*)(p0);
        bq[1] = *(const half8*)(p0 + 512);
        bq[2] = *(const half8*)(p1);
        bq[3] = *(const half8*)(p1 + 512);
    };

    auto BODY = [&](int kt, const half8* bq, half8* bqn) {
        const _Float16* Ab = &As[kt & 3][0];
        half8 a[4][2];
        #pragma unroll
        for (int i = 0; i < 4; ++i)
            #pragma unroll
            for (int s = 0; s < 2; ++s)
                a[i][s] = *(const half8*)(Ab + (size_t)(((wr * 4 + i) * 128 + s * 64 + lane) * 8));
        STAGE(kt + 3);
        LOADB(bqn, kt + 1);
        __builtin_amdgcn_s_setprio(1);
        #pragma unroll
        for (int s = 0; s < 2; ++s)
            #pragma unroll
            for (int i = 0; i < 4; ++i)
                #pragma unroll
                for (int j = 0; j < 2; ++j)
                    acc[i][j] = __builtin_amdgcn_mfma_f32_32x32x16_f16(
                        a[i][s], bq[j * 2 + s], acc[i][j], 0, 0, 0);
        __builtin_amdgcn_s_setprio(0);
        __builtin_amdgcn_sched_barrier(0);
        asm volatile("s_waitcnt vmcnt(6)" ::: "memory");  // retires A-st(kt+2)+B(kt)
        __builtin_amdgcn_s_barrier();
        __builtin_amdgcn_sched_barrier(0);
    };

    // prologue: stage A tiles 0,1,2; load B(0); certify tile 0 (vmcnt(8))
    STAGE(0); STAGE(1); STAGE(2);
    LOADB(b0, 0);
    asm volatile("s_waitcnt vmcnt(8)" ::: "memory");
    __builtin_amdgcn_s_barrier();
    __builtin_amdgcn_sched_barrier(0);

    for (int kt = 0; kt < 128; kt += 2) {
        BODY(kt, b0, b1);
        BODY(kt + 1, b1, b0);
    }

    // epilogue: 32x32 C/D layout col = lane&31, row = (reg&3)+8*(reg>>2)+4*(lane>>5)
    const int colb = bn * 256 + wc * 64 + (lane & 31);
    const int rowb = bm * 256 + wr * 128 + 4 * (lane >> 5);
    #pragma unroll
    for (int j = 0; j < 2; ++j) {
        const int col = colb + j * 32;
        const float lb = linb[col];
        #pragma unroll
        for (int i = 0; i < 4; ++i) {
            #pragma unroll
            for (int reg = 0; reg < 16; ++reg) {
                const int row = rowb + i * 32 + (reg & 3) + 8 * (reg >> 2);
                out[(size_t)row * N_DIM + col] = acc[i][j][reg] + lb;
            }
        }
    }
}

// ---------- fallback (round-3 verified): fused-dequant 128x128 2-phase ----------
#define BM 128
#define BN 128
#define BK 64
#define NKT (K_DIM / BK)

__global__ __launch_bounds__(256)
void cvt_x(const float* __restrict__ x, _Float16* __restrict__ xh) {
    size_t i = (size_t)blockIdx.x * blockDim.x + threadIdx.x;
    const float4* p = (const float4*)(x + i * 8);
    float4 a = p[0], b = p[1];
    H8 h;
    h.h2[0] = __floats2half2_rn(a.x, b.x);
    h.h2[1] = __floats2half2_rn(a.y, b.y);
    h.h2[2] = __floats2half2_rn(a.z, b.z);
    h.h2[3] = __floats2half2_rn(a.w, b.w);
    *(half8*)(xh + i * 8) = h.v;
}

__global__ __launch_bounds__(256, 2)
void qlin_f16(const _Float16* __restrict__ xh,
              const uint32_t* __restrict__ qw,
              const float* __restrict__ scales,
              const float* __restrict__ biases,
              const float* __restrict__ linb,
              float* __restrict__ out)
{
    __shared__ _Float16 Asf[2][BM * BK];
    __shared__ _Float16 Bsf[2][BN * BK];

    const int NBN = N_DIM / BN;
    const int bn = blockIdx.x % NBN;
    const int bm = blockIdx.x / NBN;
    const int tid  = threadIdx.x;
    const int lane = tid & 63;
    const int wv   = tid >> 6;
    const int wm   = (wv >> 1) * 64;
    const int wn   = (wv & 1) * 64;

    const int arow = wv * 32 + (lane >> 3);
    const int acs  = ((lane & 7) ^ ((lane >> 3) & 7)) * 8;
    const _Float16* aSrc = xh + (size_t)(bm * BM + arow) * K_DIM + acs;

    const int srow = tid >> 1;
    const int bsel = tid & 1;
    const uint32_t* qB = qw + (size_t)(bn * BN + srow) * WPR + bsel * 4;
    const float*    sB = scales + (size_t)(bn * BN + srow) * NGRP;
    const float*    bB = biases + (size_t)(bn * BN + srow) * NGRP;
    const int bwbase = srow * BK;
    const int bswz   = srow & 7;

    floatx4 acc[4][4] = {};
    uint4 q0, q1; float s0, b0, s1, b1;

    auto LOADB = [&](uint4& qr, float& s, float& bb, int kt) {
        qr = *(const uint4*)(qB + kt * 8);
        s = sB[kt >> 1]; bb = bB[kt >> 1];
    };
    auto GLOADA = [&](int buf, int kt) {
        const _Float16* sp = aSrc + (size_t)kt * BK;
        #pragma unroll
        for (int j = 0; j < 4; ++j)
            GLOAD16(sp + (size_t)j * 8 * K_DIM, &Asf[buf][wv * 2048 + j * 512]);
    };
    auto DEQ = [&](const uint4& qr, float sf, float bf, int buf) {
        const __half2 s2 = __half2half2(__float2half(sf));
        const __half2 b2 = __half2half2(__float2half(bf));
        const __half2 c1024 = __float2half2_rn(1024.0f);
        const uint32_t uws[4] = {qr.x, qr.y, qr.z, qr.w};
        #pragma unroll
        for (int wi = 0; wi < 4; ++wi) {
            const uint32_t u = uws[wi];
            H8 h;
            #pragma unroll
            for (int p = 0; p < 4; ++p) {
                const uint32_t v = ((u >> (4 * p)) & 0x000F000Fu) | 0x64006400u;
                const __half2 q2 = __hsub2(__builtin_bit_cast(__half2, v), c1024);
                h.h2[p] = __hfma2(s2, q2, b2);
            }
            const int c = bsel * 4 + wi;
            *(half8*)&Bsf[buf][bwbase + ((c ^ bswz) * 8)] = h.v;
        }
    };
    const int fr = lane & 15;
    const int kq = lane >> 4;
    auto COMPUTE = [&](int buf) {
        const _Float16* Ab = &Asf[buf][0];
        const _Float16* Bb = &Bsf[buf][0];
        #pragma unroll
        for (int ks = 0; ks < 2; ++ks) {
            half8 af[4], bf[4];
            const int csx = ks * 4 + kq;
            #pragma unroll
            for (int i = 0; i < 4; ++i) {
                const int r = wm + i * 16 + fr;
                af[i] = *(const half8*)(Ab + r * BK + ((csx ^ (r & 7)) * 8));
            }
            #pragma unroll
            for (int i = 0; i < 4; ++i) {
                const int r = wn + i * 16 + fr;
                bf[i] = *(const half8*)(Bb + r * BK + ((csx ^ (r & 7)) * 8));
            }
            #pragma unroll
            for (int mf = 0; mf < 4; ++mf)
                #pragma unroll
                for (int nf = 0; nf < 4; ++nf)
                    acc[mf][nf] = __builtin_amdgcn_mfma_f32_16x16x32_f16(
                        af[mf], bf[nf], acc[mf][nf], 0, 0, 0);
        }
    };

    LOADB(q0, s0, b0, 0);
    GLOADA(0, 0);
    DEQ(q0, s0, b0, 0);
    LOADB(q0, s0, b0, 1);
    __syncthreads();
    for (int kt = 0; kt < NKT; kt += 2) {
        GLOADA(1, kt + 1);
        if (kt + 2 < NKT) LOADB(q1, s1, b1, kt + 2);
        DEQ(q0, s0, b0, 1);
        COMPUTE(0);
        __syncthreads();
        if (kt + 2 < NKT) {
            GLOADA(0, kt + 2);
            if (kt + 3 < NKT) LOADB(q0, s0, b0, kt + 3);
            DEQ(q1, s1, b1, 0);
        }
        COMPUTE(1);
        if (kt + 2 < NKT) __syncthreads();
    }
    const int rb = bm * BM + wm + ((lane >> 4) << 2);
    const int cb = bn * BN + wn + (lane & 15);
    #pragma unroll
    for (int nf = 0; nf < 4; ++nf) {
        const int col = cb + nf * 16;
        const float lb = linb[col];
        #pragma unroll
        for (int mf = 0; mf < 4; ++mf) {
            const int row = rb + mf * 16;
            #pragma unroll
            for (int j = 0; j < 4; ++j)
                out[(size_t)(row + j) * N_DIM + col] = acc[mf][nf][j] + lb;
        }
    }
}

extern "C" void kernel_launch(void* const* d_in, const int* in_sizes, int n_in,
                              void* d_out, int out_size, void* d_ws, size_t ws_size,
                              hipStream_t stream) {
    const float*    x      = (const float*)d_in[0];
    const uint32_t* qw     = (const uint32_t*)d_in[1];
    const float*    scales = (const float*)d_in[2];
    const float*    biases = (const float*)d_in[3];
    const float*    linb   = (const float*)d_in[4];
    float*          out    = (float*)d_out;

    const int M = in_sizes[0] / K_DIM;                      // 8192
    const size_t needX = (size_t)M * K_DIM * sizeof(_Float16);
    const size_t needW = (size_t)N_DIM * K_DIM * sizeof(_Float16);

    if (ws_size >= needX + needW && (M % 256) == 0) {
        _Float16* xh = (_Float16*)d_ws;
        _Float16* wh = xh + (size_t)M * K_DIM;
        cvt_x2<<<(unsigned)((size_t)M * 512 / 256), 256, 0, stream>>>(x, xh);
        deq_w2<<<(unsigned)((size_t)N_DIM * 512 / 256), 256, 0, stream>>>(qw, scales, biases, wh);
        dim3 grid((M / 256) * (N_DIM / 256));               // 32*43 = 1376
        qlin9<<<grid, 512, 0, stream>>>(xh, wh, linb, out);
    } else if (ws_size >= needX && (M % BM) == 0) {
        _Float16* xh = (_Float16*)d_ws;
        cvt_x<<<(unsigned)((size_t)M * K_DIM / 8 / 256), 256, 0, stream>>>(x, xh);
        dim3 grid((M / BM) * (N_DIM / BN));
        qlin_f16<<<grid, 256, 0, stream>>>(xh, qw, scales, biases, linb, out);
    }
}